// Round 6
// baseline (406.154 us; speedup 1.0000x reference)
//
#include <hip/hip_runtime.h>
#include <math.h>

#define T_TOKENS 4096
#define HIDDEN   2048
#define N_EXPERTS 8
#define N_ROWS   (N_EXPERTS * T_TOKENS)   // 32768 rows of router_indices
#define ROW_F4   (HIDDEN / 4)             // 512 float4 per row

// R8 = DIAGNOSTIC. R5 proved the fill drains at ~7 TB/s (marginal pass =
// 38.4 us). By elimination the router GEMV costs ~65-75 us in EVERY
// structure tried (model says 5-10). It has never been visible in the
// top-5 counter rows (cutoff ~167 us = harness poison fills). So: run the
// EXACT R4 router wrapped in REP=6 idempotent repetitions -> if it is
// structurally slow (~70 us/rep) the dispatch is ~420+ us, top-1, and we
// finally get its VALUBusy / Occupancy / FETCH_SIZE / LDS_CONFLICT.
// Outcome decode: total ~750 -> slow every rep (read counters);
// total ~355 -> cold-path only (rep 1 slow, warm reps fast);
// total ~315 -> router was always fast, floor model is wrong.
#define REP 6

__global__ __launch_bounds__(256) void router_rep_kernel(
    const float* __restrict__ h, const float* __restrict__ w,
    float* __restrict__ out0, float* __restrict__ out2)
{
    const int wave = threadIdx.x >> 6;
    const int lane = threadIdx.x & 63;
    const int t0   = (blockIdx.x * 4 + wave) * 4;   // 256 blocks * 16 tokens

    const float4* h4 = (const float4*)h;
    const float4* w4 = (const float4*)w;

    for (int rep = 0; rep < REP; ++rep) {
        // Defeat cross-rep CSE/hoisting: memory clobber forces reloads of h/W.
        asm volatile("" ::: "memory");
        // Opaque zero so accumulator init can't be folded across reps.
        float z = 0.f;
        asm volatile("" : "+v"(z));

        float acc[4][N_EXPERTS];
        #pragma unroll
        for (int t = 0; t < 4; t++)
            #pragma unroll
            for (int e = 0; e < N_EXPERTS; e++) acc[t][e] = z;

        #pragma unroll
        for (int k = 0; k < 8; k++) {
            float4 hv[4];
            #pragma unroll
            for (int t = 0; t < 4; t++)
                hv[t] = h4[(size_t)(t0 + t) * ROW_F4 + k * 64 + lane];
            #pragma unroll
            for (int e = 0; e < N_EXPERTS; e++) {
                float4 wv = w4[e * ROW_F4 + k * 64 + lane];
                #pragma unroll
                for (int t = 0; t < 4; t++)
                    acc[t][e] += hv[t].x * wv.x + hv[t].y * wv.y
                               + hv[t].z * wv.z + hv[t].w * wv.w;
            }
        }

        // 64-lane shuffle reduction for all 32 accumulators
        #pragma unroll
        for (int t = 0; t < 4; t++)
            #pragma unroll
            for (int e = 0; e < N_EXPERTS; e++)
                #pragma unroll
                for (int off = 32; off > 0; off >>= 1)
                    acc[t][e] += __shfl_down(acc[t][e], off, 64);

        if (lane == 0) {
            #pragma unroll
            for (int t = 0; t < 4; t++) {
                const int tok = t0 + t;
                // top-2 of 8; strict > keeps first index on ties (== lax.top_k)
                int i1 = 0; float v1 = acc[t][0];
                #pragma unroll
                for (int e = 1; e < N_EXPERTS; e++)
                    if (acc[t][e] > v1) { v1 = acc[t][e]; i1 = e; }
                int i2 = -1; float v2 = -INFINITY;
                #pragma unroll
                for (int e = 0; e < N_EXPERTS; e++)
                    if (e != i1 && acc[t][e] > v2) { v2 = acc[t][e]; i2 = e; }

                float s1 = 1.f / (1.f + expf(-v1));
                float s2 = 1.f / (1.f + expf(-v2));

                #pragma unroll
                for (int e = 0; e < N_EXPERTS; e++) {
                    float val = (e == i1) ? s1 : ((e == i2) ? s2 : 0.f);
                    out0[e * T_TOKENS + tok] = val;   // same value every rep
                    out2[e * T_TOKENS + tok] = val;
                }
            }
        }
    }
}

// Pure write stream, known-good at ~38-40 us (R5 marginal measurement).
__global__ __launch_bounds__(256) void fill_kernel(float* __restrict__ out1)
{
    const int wave = threadIdx.x >> 6;
    const int lane = threadIdx.x & 63;
    const int gw   = blockIdx.x * 4 + wave;   // 0..8191
    const int r0   = gw * 4;

    float4* o4 = (float4*)out1;
    #pragma unroll
    for (int i = 0; i < 4; i++) {
        float v = (float)((r0 + i) & (T_TOKENS - 1));
        float4 vv = make_float4(v, v, v, v);
        float4* rowp = o4 + (size_t)(r0 + i) * ROW_F4;
        #pragma unroll
        for (int j = 0; j < 8; j++)
            rowp[j * 64 + lane] = vv;
    }
}

extern "C" void kernel_launch(void* const* d_in, const int* in_sizes, int n_in,
                              void* d_out, int out_size, void* d_ws, size_t ws_size,
                              hipStream_t stream) {
    const float* h = (const float*)d_in[0];   // [4096, 2048] f32
    const float* w = (const float*)d_in[1];   // [8, 2048] f32
    // d_in[2] = top_k (always 2 for this problem)

    float* out  = (float*)d_out;
    float* out0 = out;                                            // router_scores [8,4096]
    float* out1 = out + N_EXPERTS * T_TOKENS;                     // router_indices [32768,2048]
    float* out2 = out1 + (size_t)N_EXPERTS * T_TOKENS * HIDDEN;   // router_probs [32768,1]

    hipLaunchKernelGGL(router_rep_kernel, dim3(256), dim3(256), 0, stream,
                       h, w, out0, out2);
    hipLaunchKernelGGL(fill_kernel, dim3(2048), dim3(256), 0, stream, out1);
}

// Round 7
// 298.203 us; speedup vs baseline: 1.3620x; 1.3620x over previous
//
#include <hip/hip_runtime.h>
#include <math.h>

#define T_TOKENS 4096
#define HIDDEN   2048
#define N_EXPERTS 8
#define N_ROWS   (N_EXPERTS * T_TOKENS)   // 32768 rows of router_indices
#define ROW_F4   (HIDDEN / 4)             // 512 float4 per row

// R9. REP-experiment decode (R6): router cost = ~50 us cold-tax + ~20 us warm.
//  - Cold-tax: the harness poison fill leaves ~288 MB dirty in L2/L3; the
//    next kernel that READS forces that to drain to HBM first (~45 us at
//    6.4 TB/s). Our fill OVERWRITES the same arena -> dirty poison lines are
//    updated in place, never drained. So: FILL RUNS FIRST (never tried in
//    R0-R6 -- every structure led with router h-reads into dirty L3).
//  - Warm 20 us: 1024 waves x 64 KB W re-read = 64 MB through the few L2
//    sets holding W (hotspot ~3-4 TB/s). Fix: W staged to LDS once per
//    block, 16 tokens/block (256 blocks, 1/CU) -> 16 MB W L2-traffic, and
//    per-k W access becomes conflict-free ds_read_b128.

// ---------------------------------------------------------------------------
// Fill: PURE write stream (proven ~38-40 us marginal, R5). Runs FIRST to
// absorb the poison drain. Plain stores (nt was 6x slower, R2).
// ---------------------------------------------------------------------------
__global__ __launch_bounds__(256) void fill_kernel(float* __restrict__ out1)
{
    const int wave = threadIdx.x >> 6;
    const int lane = threadIdx.x & 63;
    const int gw   = blockIdx.x * 4 + wave;   // 0..8191
    const int r0   = gw * 4;

    float4* o4 = (float4*)out1;
    #pragma unroll
    for (int i = 0; i < 4; i++) {
        float v = (float)((r0 + i) & (T_TOKENS - 1));
        float4 vv = make_float4(v, v, v, v);
        float4* rowp = o4 + (size_t)(r0 + i) * ROW_F4;
        #pragma unroll
        for (int j = 0; j < 8; j++)
            rowp[j * 64 + lane] = vv;
    }
}

// ---------------------------------------------------------------------------
// Router: 256 blocks x 256 (1 block/CU). W (64 KB) staged to LDS once per
// block; 16 tokens/block = 4/wave. Per k-step: 4 h float4 loads (stream) +
// 8 conflict-free ds_read_b128 + 128 FMA. W L2-traffic: 256 x 64 KB = 16 MB.
// ---------------------------------------------------------------------------
__global__ __launch_bounds__(256) void router_kernel(
    const float* __restrict__ h, const float* __restrict__ w,
    float* __restrict__ out0, float* __restrict__ out2)
{
    __shared__ float wlds[N_EXPERTS * HIDDEN];  // 64 KB
    {
        const float4* w4  = (const float4*)w;
        float4*       wl4 = (float4*)wlds;
        for (int i = threadIdx.x; i < (N_EXPERTS * HIDDEN) / 4; i += 256)
            wl4[i] = w4[i];
    }
    __syncthreads();

    const int wave = threadIdx.x >> 6;
    const int lane = threadIdx.x & 63;
    const int t0   = blockIdx.x * 16 + wave * 4;   // 256 blocks * 16 tokens

    const float4* h4  = (const float4*)h;
    const float4* wl4 = (const float4*)wlds;

    float acc[4][N_EXPERTS];
    #pragma unroll
    for (int t = 0; t < 4; t++)
        #pragma unroll
        for (int e = 0; e < N_EXPERTS; e++) acc[t][e] = 0.f;

    #pragma unroll
    for (int k = 0; k < 8; k++) {
        float4 hv[4];
        #pragma unroll
        for (int t = 0; t < 4; t++)
            hv[t] = h4[(size_t)(t0 + t) * ROW_F4 + k * 64 + lane];
        #pragma unroll
        for (int e = 0; e < N_EXPERTS; e++) {
            float4 wv = wl4[e * 512 + k * 64 + lane];
            #pragma unroll
            for (int t = 0; t < 4; t++)
                acc[t][e] += hv[t].x * wv.x + hv[t].y * wv.y
                           + hv[t].z * wv.z + hv[t].w * wv.w;
        }
    }

    // 64-lane shuffle reduction for all 32 accumulators
    #pragma unroll
    for (int t = 0; t < 4; t++)
        #pragma unroll
        for (int e = 0; e < N_EXPERTS; e++)
            #pragma unroll
            for (int off = 32; off > 0; off >>= 1)
                acc[t][e] += __shfl_down(acc[t][e], off, 64);

    if (lane == 0) {
        #pragma unroll
        for (int t = 0; t < 4; t++) {
            const int tok = t0 + t;
            // top-2 of 8; strict > keeps first index on ties (== lax.top_k)
            int i1 = 0; float v1 = acc[t][0];
            #pragma unroll
            for (int e = 1; e < N_EXPERTS; e++)
                if (acc[t][e] > v1) { v1 = acc[t][e]; i1 = e; }
            int i2 = -1; float v2 = -INFINITY;
            #pragma unroll
            for (int e = 0; e < N_EXPERTS; e++)
                if (e != i1 && acc[t][e] > v2) { v2 = acc[t][e]; i2 = e; }

            float s1 = 1.f / (1.f + expf(-v1));
            float s2 = 1.f / (1.f + expf(-v2));

            #pragma unroll
            for (int e = 0; e < N_EXPERTS; e++) {
                float val = (e == i1) ? s1 : ((e == i2) ? s2 : 0.f);
                out0[e * T_TOKENS + tok] = val;
                out2[e * T_TOKENS + tok] = val;
            }
        }
    }
}

extern "C" void kernel_launch(void* const* d_in, const int* in_sizes, int n_in,
                              void* d_out, int out_size, void* d_ws, size_t ws_size,
                              hipStream_t stream) {
    const float* h = (const float*)d_in[0];   // [4096, 2048] f32
    const float* w = (const float*)d_in[1];   // [8, 2048] f32
    // d_in[2] = top_k (always 2 for this problem)

    float* out  = (float*)d_out;
    float* out0 = out;                                            // router_scores [8,4096]
    float* out1 = out + N_EXPERTS * T_TOKENS;                     // router_indices [32768,2048]
    float* out2 = out1 + (size_t)N_EXPERTS * T_TOKENS * HIDDEN;   // router_probs [32768,1]

    // FILL FIRST: overwrites the poison-dirty arena in-cache (drain cancel).
    hipLaunchKernelGGL(fill_kernel, dim3(2048), dim3(256), 0, stream, out1);
    hipLaunchKernelGGL(router_kernel, dim3(256), dim3(256), 0, stream,
                       h, w, out0, out2);
}